// Round 1
// 981.446 us; speedup vs baseline: 1.0591x; 1.0591x over previous
//
#include <hip/hip_runtime.h>

// ---------------------------------------------------------------------------
// FullMHA: x(32,512,2048) fp32, w_qkv(6144,2048), w_out(2048,2048)
// qkv = x @ w_qkv^T ; RoPE(64) on q,k ; causal softmax(QK^T/sqrt(128))V ;
// out = y @ w_out^T.  All GEMMs in bf16 MFMA (16x16x32), fp32 accumulate.
// R3: GEMMs rebuilt on the 256x256 / BK=64 / 8-wave counted-vmcnt schedule
//     (T1 XCD swizzle + T2 LDS swizzle + T3/T4 4-phase counted vmcnt + T5
//     setprio). One s_waitcnt vmcnt(6) per K-tile, never a full drain in the
//     steady-state loop. Attention kernel unchanged from R2.
// ---------------------------------------------------------------------------

typedef __bf16 bf16x8 __attribute__((ext_vector_type(8)));
typedef float floatx4 __attribute__((ext_vector_type(4)));

__device__ __forceinline__ unsigned short f2bf(float f) {
  union { float f; unsigned u; } v; v.f = f;
  unsigned r = v.u + 0x7FFFu + ((v.u >> 16) & 1u);   // RNE
  return (unsigned short)(r >> 16);
}
__device__ __forceinline__ float bf2f(unsigned short h) {
  union { unsigned u; float f; } v; v.u = ((unsigned)h) << 16; return v.f;
}

__device__ __forceinline__ void load_lds16(const void* g, void* l) {
  __builtin_amdgcn_global_load_lds((__attribute__((address_space(1))) void*)g,
                                   (__attribute__((address_space(3))) void*)l,
                                   16, 0, 0);
}

#define BARRIER() asm volatile("s_barrier" ::: "memory")
#define VMCNT6()  asm volatile("s_waitcnt vmcnt(6)" ::: "memory")
#define VMCNT0()  asm volatile("s_waitcnt vmcnt(0)" ::: "memory")
#define LGKM0()   asm volatile("s_waitcnt lgkmcnt(0)" ::: "memory")

// ---------------- RoPE tables ----------------------------------------------
__global__ void rope_tables(float* __restrict__ cost, float* __restrict__ sint) {
  int i = blockIdx.x * 256 + threadIdx.x;
  if (i >= 512 * 32) return;
  int t = i >> 5, f = i & 31;
  float e = -(float)(2 * f) / 64.0f;
  float freq = powf(10000.0f, e);
  float ang = (float)t * freq;
  cost[i] = cosf(ang);
  sint[i] = sinf(ang);
}

// ---------------- fp32 -> bf16 cast, 8 elems/thread ------------------------
__global__ void cast_bf16(const float* __restrict__ in,
                          unsigned short* __restrict__ out, int n8) {
  int i = blockIdx.x * 256 + threadIdx.x;
  if (i >= n8) return;
  float4 a = ((const float4*)in)[2 * i];
  float4 b = ((const float4*)in)[2 * i + 1];
  union { uint4 v; unsigned short u[8]; } o;
  o.u[0] = f2bf(a.x); o.u[1] = f2bf(a.y); o.u[2] = f2bf(a.z); o.u[3] = f2bf(a.w);
  o.u[4] = f2bf(b.x); o.u[5] = f2bf(b.y); o.u[6] = f2bf(b.z); o.u[7] = f2bf(b.w);
  ((uint4*)out)[i] = o.v;
}

// ---------------- GEMM: C[M,N] = A[M,K] * Bt[N,K]^T  (bf16, 256^2 8-wave) --
// 512 threads = 8 waves (2M x 4N), per-wave output 128x64, BK=64.
// LDS: 2 buffers x (A 256x64 + B 256x64) bf16 = 128 KiB. 16B chunk c of row
// r stored at c^(r&7) (conflict-free ds_read_b128; staging pre-swizzles the
// global source chunk so linear global_load_lds lands swizzled).
//
// Per K-tile t (buffer q=t&1), 4 phases; stage order (1 half-tile each):
//   ph1: read ALL A frags + B nh0; stage B-hi(t+1) -> buf q^1
//   ph2: MFMA (mh1,nh0);           stage A-lo(t+2) -> buf q   (A fully read)
//   ph3: read B nh1;  MFMA;        stage A-hi(t+2) -> buf q
//   ph4: MFMA (mh1,nh1);           stage B-lo(t+2) -> buf q   (B fully read)
//   then s_waitcnt vmcnt(6): retires exactly tile t+1's 8 loads, leaves
//   t+2's 3 half-tiles (6 loads) in flight. Raw s_barrier (asm, memory
//   clobber) so the compiler never inserts a vmcnt(0) drain.
template <int OUT_BF16>
__global__ __launch_bounds__(512, 2) void gemm256(
    const unsigned short* __restrict__ A, const unsigned short* __restrict__ Bt,
    void* __restrict__ Cout, int M, int N, int K) {
  __shared__ __align__(16) unsigned short As[2][16384];
  __shared__ __align__(16) unsigned short Bs[2][16384];

  const int tid = threadIdx.x;
  // XCD-aware bijective swizzle (nwg % 8 == 0 for both call sites)
  const int nbx = gridDim.x;
  const int nwg = nbx * gridDim.y;
  const int lin = blockIdx.y * nbx + blockIdx.x;
  const int swz = (lin & 7) * (nwg >> 3) + (lin >> 3);
  const int bm = swz / nbx, bn = swz % nbx;

  const int w = tid >> 6, l = tid & 63;
  const int wm = w >> 2, wn = w & 3;      // 2 x 4 wave grid
  const int quad = l >> 4, cl = l & 15;
  const int xs0 = ((0 + quad) ^ (cl & 7)) << 3;  // swizzled k-chunk, ks=0
  const int xs1 = ((4 + quad) ^ (cl & 7)) << 3;  // ks=1
  const int aoff = (wm * 128 + cl) * 64;
  const int boff = (wn * 64 + cl) * 64;

  // staging map: thread tid covers LDS bytes [tid*16, +16) of a half-tile
  const int srow = tid >> 3;                    // 0..63
  const int lc = (tid & 7) ^ (srow & 7);        // pre-swizzled source chunk
  const unsigned short* Ag = A + (size_t)(bm * 256 + srow) * K + lc * 8;
  const unsigned short* Bg = Bt + (size_t)(bn * 256 + srow) * K + lc * 8;

  auto stageA = [&](int q, int h, int k0) {
    const unsigned short* src = Ag + (size_t)(h * 128) * K + k0;
    unsigned short* dst = &As[q][0] + h * 8192 + tid * 8;
    load_lds16(src, dst);
    load_lds16(src + (size_t)64 * K, dst + 4096);
  };
  auto stageB = [&](int q, int h, int k0) {
    const unsigned short* src = Bg + (size_t)(h * 128) * K + k0;
    unsigned short* dst = &Bs[q][0] + h * 8192 + tid * 8;
    load_lds16(src, dst);
    load_lds16(src + (size_t)64 * K, dst + 4096);
  };

  floatx4 acc[8][4] = {};
  const int NT = K >> 6;

  // -------- prologue: tile0 (4 half-tiles) + tile1 (3 half-tiles) ----------
  stageA(0, 0, 0);  stageA(0, 1, 0);  stageB(0, 0, 0);  stageB(0, 1, 0);
  stageA(1, 0, 64); stageA(1, 1, 64); stageB(1, 0, 64);
  VMCNT6();   // retire tile0's 8 loads; tile1's 6 stay in flight
  BARRIER();

  for (int t = 0; t < NT; ++t) {
    const int q = t & 1;
    const unsigned short* pA = &As[q][0] + aoff;
    const unsigned short* pB = &Bs[q][0] + boff;
    const int k2 = (t + 2) << 6;
    const bool s2 = (t + 2) < NT;

    bf16x8 a[8][2], b[2][2];
    // ---------------- phase 1: (mh0, nh0) --------------------------------
#pragma unroll
    for (int mi = 0; mi < 8; ++mi) {
      a[mi][0] = *(const bf16x8*)(pA + mi * 1024 + xs0);
      a[mi][1] = *(const bf16x8*)(pA + mi * 1024 + xs1);
    }
#pragma unroll
    for (int ni = 0; ni < 2; ++ni) {
      b[ni][0] = *(const bf16x8*)(pB + ni * 1024 + xs0);
      b[ni][1] = *(const bf16x8*)(pB + ni * 1024 + xs1);
    }
    if (t + 1 < NT) stageB(q ^ 1, 1, (t + 1) << 6);
    BARRIER();
    __builtin_amdgcn_s_setprio(1);
#pragma unroll
    for (int mi = 0; mi < 4; ++mi)
#pragma unroll
      for (int ni = 0; ni < 2; ++ni)
#pragma unroll
        for (int ks = 0; ks < 2; ++ks)
          acc[mi][ni] = __builtin_amdgcn_mfma_f32_16x16x32_bf16(
              a[mi][ks], b[ni][ks], acc[mi][ni], 0, 0, 0);
    __builtin_amdgcn_s_setprio(0);
    LGKM0();   // drain a[4..7] reads before any wave's ph2 stage can land
    BARRIER();
    // ---------------- phase 2: (mh1, nh0) --------------------------------
    if (s2) stageA(q, 0, k2);
    BARRIER();
    __builtin_amdgcn_s_setprio(1);
#pragma unroll
    for (int mi = 4; mi < 8; ++mi)
#pragma unroll
      for (int ni = 0; ni < 2; ++ni)
#pragma unroll
        for (int ks = 0; ks < 2; ++ks)
          acc[mi][ni] = __builtin_amdgcn_mfma_f32_16x16x32_bf16(
              a[mi][ks], b[ni][ks], acc[mi][ni], 0, 0, 0);
    __builtin_amdgcn_s_setprio(0);
    BARRIER();
    // ---------------- phase 3: (mh0, nh1) --------------------------------
#pragma unroll
    for (int ni = 0; ni < 2; ++ni) {
      b[ni][0] = *(const bf16x8*)(pB + (ni + 2) * 1024 + xs0);
      b[ni][1] = *(const bf16x8*)(pB + (ni + 2) * 1024 + xs1);
    }
    if (s2) stageA(q, 1, k2);
    BARRIER();
    __builtin_amdgcn_s_setprio(1);
#pragma unroll
    for (int mi = 0; mi < 4; ++mi)
#pragma unroll
      for (int ni = 0; ni < 2; ++ni)
#pragma unroll
        for (int ks = 0; ks < 2; ++ks)
          acc[mi][ni + 2] = __builtin_amdgcn_mfma_f32_16x16x32_bf16(
              a[mi][ks], b[ni][ks], acc[mi][ni + 2], 0, 0, 0);
    __builtin_amdgcn_s_setprio(0);
    BARRIER();
    // ---------------- phase 4: (mh1, nh1) --------------------------------
    if (s2) stageB(q, 0, k2);
    BARRIER();
    __builtin_amdgcn_s_setprio(1);
#pragma unroll
    for (int mi = 4; mi < 8; ++mi)
#pragma unroll
      for (int ni = 0; ni < 2; ++ni)
#pragma unroll
        for (int ks = 0; ks < 2; ++ks)
          acc[mi][ni + 2] = __builtin_amdgcn_mfma_f32_16x16x32_bf16(
              a[mi][ks], b[ni][ks], acc[mi][ni + 2], 0, 0, 0);
    __builtin_amdgcn_s_setprio(0);
    if (t < NT - 2) { VMCNT6(); } else { VMCNT0(); }
    BARRIER();
  }

  // -------- epilogue -------------------------------------------------------
#pragma unroll
  for (int mi = 0; mi < 8; ++mi)
#pragma unroll
    for (int ni = 0; ni < 4; ++ni)
#pragma unroll
      for (int r = 0; r < 4; ++r) {
        const int gm = bm * 256 + wm * 128 + mi * 16 + quad * 4 + r;
        const int gn = bn * 256 + wn * 64 + ni * 16 + cl;
        const float v = acc[mi][ni][r];
        if (OUT_BF16)
          ((unsigned short*)Cout)[(size_t)gm * N + gn] = f2bf(v);
        else
          ((float*)Cout)[(size_t)gm * N + gn] = v;
      }
}

// ---------------- Fused RoPE + causal flash attention ----------------------
// grid (B*H=512, T/64=8), 256 threads = 4 waves, wave w owns q-rows w*16..+16.
// Softmax kept in log2 domain: log2(e)/sqrt(128) folded into Q scale.
__global__ __launch_bounds__(256) void attn_kernel(
    const unsigned short* __restrict__ qkv, const float* __restrict__ cost,
    const float* __restrict__ sint, unsigned short* __restrict__ y) {
  __shared__ __align__(16) unsigned short Qs[64][136];
  __shared__ __align__(16) unsigned short Ks[64][136];
  __shared__ __align__(16) unsigned short VTs[128][64];  // chunk-swizzled
  __shared__ __align__(16) unsigned short Ps[4][16][72];

  const int bh = blockIdx.x, qt = blockIdx.y;
  const int b = bh >> 4, h = bh & 15;
  const int tid = threadIdx.x, w = tid >> 6, l = tid & 63;
  const int quad = l >> 4, cl = l & 15;
  // 1/sqrt(128) * log2(e)  (softmax in exp2 domain)
  const float scale = 0.08838834764831845f * 1.4426950408889634f;

  // ---- Q tile: load + RoPE + scale, vector LDS writes ----
  {
    const int r = tid >> 2, j = tid & 3;
    const int tg = qt * 64 + r;
    const unsigned short* qrow = qkv + (size_t)(b * 512 + tg) * 6144 + h * 128;
    union { uint4 v; unsigned short u[8]; } c1, c2, p1, p2, o1, o2, o3, o4;
    c1.v = *(const uint4*)(qrow + j * 8);
    c2.v = *(const uint4*)(qrow + j * 8 + 32);
    p1.v = *(const uint4*)(qrow + 64 + j * 16);
    p2.v = *(const uint4*)(qrow + 64 + j * 16 + 8);
#pragma unroll
    for (int jj = 0; jj < 8; ++jj) {
      int d = j * 8 + jj;
      float c = cost[tg * 32 + d], s = sint[tg * 32 + d];
      float x1 = bf2f(c1.u[jj]), x2 = bf2f(c2.u[jj]);
      o1.u[jj] = f2bf((x1 * c - x2 * s) * scale);
      o2.u[jj] = f2bf((x2 * c + x1 * s) * scale);
      o3.u[jj] = f2bf(bf2f(p1.u[jj]) * scale);
      o4.u[jj] = f2bf(bf2f(p2.u[jj]) * scale);
    }
    *(uint4*)&Qs[r][j * 8]          = o1.v;
    *(uint4*)&Qs[r][j * 8 + 32]     = o2.v;
    *(uint4*)&Qs[r][64 + j * 16]     = o3.v;
    *(uint4*)&Qs[r][64 + j * 16 + 8] = o4.v;
  }

  floatx4 o[8] = {};
  float m_i[4] = {-__builtin_inff(), -__builtin_inff(), -__builtin_inff(),
                  -__builtin_inff()};
  float l_i[4] = {0.f, 0.f, 0.f, 0.f};

  for (int ktile = 0; ktile <= qt; ++ktile) {
    __syncthreads();  // (A) previous PV done reading Ks/VTs
    {  // K tile: load + RoPE, vector LDS writes
      const int r = tid >> 2, j = tid & 3;
      const int tg = ktile * 64 + r;
      const unsigned short* krow =
          qkv + (size_t)(b * 512 + tg) * 6144 + 2048 + h * 128;
      union { uint4 v; unsigned short u[8]; } c1, c2, p1, p2, o1, o2;
      c1.v = *(const uint4*)(krow + j * 8);
      c2.v = *(const uint4*)(krow + j * 8 + 32);
      p1.v = *(const uint4*)(krow + 64 + j * 16);
      p2.v = *(const uint4*)(krow + 64 + j * 16 + 8);
#pragma unroll
      for (int jj = 0; jj < 8; ++jj) {
        int d = j * 8 + jj;
        float c = cost[tg * 32 + d], s = sint[tg * 32 + d];
        float x1 = bf2f(c1.u[jj]), x2 = bf2f(c2.u[jj]);
        o1.u[jj] = f2bf(x1 * c - x2 * s);
        o2.u[jj] = f2bf(x2 * c + x1 * s);
      }
      *(uint4*)&Ks[r][j * 8]          = o1.v;
      *(uint4*)&Ks[r][j * 8 + 32]     = o2.v;
      *(uint4*)&Ks[r][64 + j * 16]     = p1.v;
      *(uint4*)&Ks[r][64 + j * 16 + 8] = p2.v;
    }
    {  // V tile -> VTs[d][kk'], 8 kk-rows x 4 d-cols per thread, swizzled
      const int rowg = tid >> 5;        // kk0 = rowg*8
      const int colg = tid & 31;        // d0 = colg*4
      const int kk0 = rowg * 8, d0 = colg * 4;
      const unsigned short* vbase = qkv +
          (size_t)(b * 512 + ktile * 64 + kk0) * 6144 + 4096 + h * 128 + d0;
      uint2 rv[8];
#pragma unroll
      for (int rr = 0; rr < 8; ++rr)
        rv[rr] = *(const uint2*)(vbase + (size_t)rr * 6144);
#pragma unroll
      for (int c = 0; c < 4; ++c) {
        const int d = d0 + c;
        unsigned out[4];
#pragma unroll
        for (int p = 0; p < 4; ++p) {
          unsigned ua = ((const unsigned*)&rv[2 * p])[c >> 1];
          unsigned ub = ((const unsigned*)&rv[2 * p + 1])[c >> 1];
          unsigned lo = (c & 1) ? (ua >> 16) : (ua & 0xffffu);
          unsigned hi = (c & 1) ? (ub >> 16) : (ub & 0xffffu);
          out[p] = lo | (hi << 16);
        }
        *(uint4*)&VTs[d][(rowg ^ (d & 7)) << 3] = *(uint4*)out;
      }
    }
    __syncthreads();  // (B) staging complete

    // S = Q K^T : wave w -> 16x64 strip
    floatx4 s[4] = {};
#pragma unroll
    for (int kc = 0; kc < 4; ++kc) {
      bf16x8 aq = *(const bf16x8*)(&Qs[w * 16 + cl][kc * 32 + quad * 8]);
#pragma unroll
      for (int nt = 0; nt < 4; ++nt) {
        bf16x8 bk = *(const bf16x8*)(&Ks[nt * 16 + cl][kc * 32 + quad * 8]);
        s[nt] = __builtin_amdgcn_mfma_f32_16x16x32_bf16(aq, bk, s[nt], 0, 0, 0);
      }
    }
    if (ktile == qt) {  // causal mask on diagonal tile
#pragma unroll
      for (int nt = 0; nt < 4; ++nt)
#pragma unroll
        for (int r = 0; r < 4; ++r) {
          int qrow_l = w * 16 + quad * 4 + r;
          int kcol_l = nt * 16 + cl;
          if (kcol_l > qrow_l) s[nt][r] = -__builtin_inff();
        }
    }
    // online softmax (exp2 domain)
#pragma unroll
    for (int r = 0; r < 4; ++r) {
      float mx = fmaxf(fmaxf(s[0][r], s[1][r]), fmaxf(s[2][r], s[3][r]));
      mx = fmaxf(mx, __shfl_xor(mx, 1));
      mx = fmaxf(mx, __shfl_xor(mx, 2));
      mx = fmaxf(mx, __shfl_xor(mx, 4));
      mx = fmaxf(mx, __shfl_xor(mx, 8));
      float mn = fmaxf(m_i[r], mx);
      float a = exp2f(m_i[r] - mn);
      float rs = 0.f;
#pragma unroll
      for (int nt = 0; nt < 4; ++nt) {
        float p = exp2f(s[nt][r] - mn);
        s[nt][r] = p;
        rs += p;
      }
      rs += __shfl_xor(rs, 1);
      rs += __shfl_xor(rs, 2);
      rs += __shfl_xor(rs, 4);
      rs += __shfl_xor(rs, 8);
      l_i[r] = l_i[r] * a + rs;
      m_i[r] = mn;
#pragma unroll
      for (int nt2 = 0; nt2 < 8; ++nt2) o[nt2][r] *= a;
#pragma unroll
      for (int nt = 0; nt < 4; ++nt)
        Ps[w][quad * 4 + r][nt * 16 + cl] = f2bf(s[nt][r]);
    }
    __syncthreads();  // (C) P visible (VTs still valid)

    // O += P V  (B operand from swizzled VTs)
#pragma unroll
    for (int kc2 = 0; kc2 < 2; ++kc2) {
      bf16x8 ap = *(const bf16x8*)(&Ps[w][cl][kc2 * 32 + quad * 8]);
#pragma unroll
      for (int nt2 = 0; nt2 < 8; ++nt2) {
        bf16x8 bv = *(const bf16x8*)(
            &VTs[nt2 * 16 + cl][((kc2 * 4 + quad) ^ (cl & 7)) << 3]);
        o[nt2] = __builtin_amdgcn_mfma_f32_16x16x32_bf16(ap, bv, o[nt2], 0, 0, 0);
      }
    }
  }

  // epilogue: y[bt][h*128+d] = o/l
#pragma unroll
  for (int r = 0; r < 4; ++r) {
    float inv = 1.0f / l_i[r];
    size_t row =
        (size_t)(b * 512 + qt * 64 + w * 16 + quad * 4 + r) * 2048 + h * 128;
#pragma unroll
    for (int nt2 = 0; nt2 < 8; ++nt2)
      y[row + nt2 * 16 + cl] = f2bf(o[nt2][r] * inv);
  }
}

// ---------------------------------------------------------------------------
extern "C" void kernel_launch(void* const* d_in, const int* in_sizes, int n_in,
                              void* d_out, int out_size, void* d_ws,
                              size_t ws_size, hipStream_t stream) {
  const float* x = (const float*)d_in[0];
  const float* wqkv = (const float*)d_in[1];
  const float* wout = (const float*)d_in[2];
  float* out = (float*)d_out;

  char* ws = (char*)d_ws;
  float* cost = (float*)ws;            ws += (size_t)512 * 32 * 4;
  float* sint = (float*)ws;            ws += (size_t)512 * 32 * 4;
  unsigned short* xb = (unsigned short*)ws;    ws += (size_t)16384 * 2048 * 2;
  unsigned short* wqkvb = (unsigned short*)ws; ws += (size_t)6144 * 2048 * 2;
  unsigned short* woutb = (unsigned short*)ws; ws += (size_t)2048 * 2048 * 2;
  unsigned short* qkvb = (unsigned short*)ws;  ws += (size_t)16384 * 6144 * 2;
  unsigned short* yb = (unsigned short*)ws;    ws += (size_t)16384 * 2048 * 2;

  rope_tables<<<dim3(64), dim3(256), 0, stream>>>(cost, sint);
  cast_bf16<<<dim3(16384), dim3(256), 0, stream>>>(x, xb, 33554432 / 8);
  cast_bf16<<<dim3(6144), dim3(256), 0, stream>>>(wqkv, wqkvb, 12582912 / 8);
  cast_bf16<<<dim3(2048), dim3(256), 0, stream>>>(wout, woutb, 4194304 / 8);
  gemm256<1><<<dim3(24, 64), dim3(512), 0, stream>>>(xb, wqkvb, (void*)qkvb,
                                                     16384, 6144, 2048);
  attn_kernel<<<dim3(512, 8), dim3(256), 0, stream>>>(qkvb, cost, sint, yb);
  gemm256<0><<<dim3(8, 64), dim3(512), 0, stream>>>(yb, woutb, (void*)out,
                                                    16384, 2048, 2048);
}

// Round 2
// 948.837 us; speedup vs baseline: 1.0955x; 1.0344x over previous
//
#include <hip/hip_runtime.h>

// ---------------------------------------------------------------------------
// FullMHA: x(32,512,2048) fp32, w_qkv(6144,2048), w_out(2048,2048)
// qkv = x @ w_qkv^T ; RoPE(64) on q,k ; causal softmax(QK^T/sqrt(128))V ;
// out = y @ w_out^T.  All GEMMs in bf16 MFMA (16x16x32), fp32 accumulate.
// R4: gemm256 ds_reads spread across phases (12/8/4/0) instead of 20 in ph1.
//     Quadrant order m0n0 -> m1n0 -> m1n1 -> m0n1; stage slots moved to
//     ph1/ph3/ph4 to keep WAR safety; same vmcnt(6)-per-tile invariant.
//     (R3 post-mortem: ph1's 160 CU-wide ds_read_b128 = ~1920 LDS-pipe
//     cycles serialized against 620-cy MFMA phases -> MfmaUtil stuck at 41%.)
// ---------------------------------------------------------------------------

typedef __bf16 bf16x8 __attribute__((ext_vector_type(8)));
typedef float floatx4 __attribute__((ext_vector_type(4)));

__device__ __forceinline__ unsigned short f2bf(float f) {
  union { float f; unsigned u; } v; v.f = f;
  unsigned r = v.u + 0x7FFFu + ((v.u >> 16) & 1u);   // RNE
  return (unsigned short)(r >> 16);
}
__device__ __forceinline__ float bf2f(unsigned short h) {
  union { unsigned u; float f; } v; v.u = ((unsigned)h) << 16; return v.f;
}

__device__ __forceinline__ void load_lds16(const void* g, void* l) {
  __builtin_amdgcn_global_load_lds((__attribute__((address_space(1))) void*)g,
                                   (__attribute__((address_space(3))) void*)l,
                                   16, 0, 0);
}

#define BARRIER() asm volatile("s_barrier" ::: "memory")
#define VMCNT6()  asm volatile("s_waitcnt vmcnt(6)" ::: "memory")
#define VMCNT0()  asm volatile("s_waitcnt vmcnt(0)" ::: "memory")

// ---------------- RoPE tables ----------------------------------------------
__global__ void rope_tables(float* __restrict__ cost, float* __restrict__ sint) {
  int i = blockIdx.x * 256 + threadIdx.x;
  if (i >= 512 * 32) return;
  int t = i >> 5, f = i & 31;
  float e = -(float)(2 * f) / 64.0f;
  float freq = powf(10000.0f, e);
  float ang = (float)t * freq;
  cost[i] = cosf(ang);
  sint[i] = sinf(ang);
}

// ---------------- fp32 -> bf16 cast, 8 elems/thread ------------------------
__global__ void cast_bf16(const float* __restrict__ in,
                          unsigned short* __restrict__ out, int n8) {
  int i = blockIdx.x * 256 + threadIdx.x;
  if (i >= n8) return;
  float4 a = ((const float4*)in)[2 * i];
  float4 b = ((const float4*)in)[2 * i + 1];
  union { uint4 v; unsigned short u[8]; } o;
  o.u[0] = f2bf(a.x); o.u[1] = f2bf(a.y); o.u[2] = f2bf(a.z); o.u[3] = f2bf(a.w);
  o.u[4] = f2bf(b.x); o.u[5] = f2bf(b.y); o.u[6] = f2bf(b.z); o.u[7] = f2bf(b.w);
  ((uint4*)out)[i] = o.v;
}

// ---------------- GEMM: C[M,N] = A[M,K] * Bt[N,K]^T  (bf16, 256^2 8-wave) --
// 512 threads = 8 waves (2M x 4N), per-wave output 128x64, BK=64.
// LDS: 2 buffers x (A 256x64 + B 256x64) bf16 = 128 KiB; 16B chunk c of row
// r stored at c^(r&7) (conflict-free ds_read_b128; staging pre-swizzles the
// global source chunk so linear global_load_lds lands swizzled).
//
// Per K-tile t (buffer q=t&1), 4 phases, quadrants m0n0/m1n0/m1n1/m0n1.
// Reads per phase: 12 / 8 / 4 / 0 b128 (each frag read in the phase that
// consumes it; a0,b0,a1,b1 stay register-live for their reuse phase).
// Stage slots (WAR-safe: half-tile of buf q only overwritten after both
// owning waves' last LDS read of it, enforced by the 2-barrier phases):
//   ph1: B-hi(t+1)->q^1   (q^1 B-hi last read tile t-1 ph3)
//   ph3: A-lo(t+2)->q     (A reads of tile t end at ph2)
//   ph4: A-hi(t+2)+B-lo(t+2)->q  (B-lo reads end at ph3)
// vmcnt(6) once per tile: 14 outstanding -> retires exactly tile t+1's 8
// loads, leaves tile t+2's 6 in flight. Never drains in steady state.
template <int OUT_BF16>
__global__ __launch_bounds__(512, 2) void gemm256(
    const unsigned short* __restrict__ A, const unsigned short* __restrict__ Bt,
    void* __restrict__ Cout, int M, int N, int K) {
  __shared__ __align__(16) unsigned short As[2][16384];
  __shared__ __align__(16) unsigned short Bs[2][16384];

  const int tid = threadIdx.x;
  // XCD-aware bijective swizzle (nwg % 8 == 0 for both call sites)
  const int nbx = gridDim.x;
  const int nwg = nbx * gridDim.y;
  const int lin = blockIdx.y * nbx + blockIdx.x;
  const int swz = (lin & 7) * (nwg >> 3) + (lin >> 3);
  const int bm = swz / nbx, bn = swz % nbx;

  const int w = tid >> 6, l = tid & 63;
  const int wm = w >> 2, wn = w & 3;      // 2 x 4 wave grid
  const int quad = l >> 4, cl = l & 15;
  const int xs0 = ((0 + quad) ^ (cl & 7)) << 3;  // swizzled k-chunk, ks=0
  const int xs1 = ((4 + quad) ^ (cl & 7)) << 3;  // ks=1
  const int aoff = (wm * 128 + cl) * 64;
  const int boff = (wn * 64 + cl) * 64;

  // staging map: thread tid covers LDS bytes [tid*16, +16) of a half-tile
  const int srow = tid >> 3;                    // 0..63
  const int lc = (tid & 7) ^ (srow & 7);        // pre-swizzled source chunk
  const unsigned short* Ag = A + (size_t)(bm * 256 + srow) * K + lc * 8;
  const unsigned short* Bg = Bt + (size_t)(bn * 256 + srow) * K + lc * 8;

  auto stageA = [&](int q, int h, int k0) {
    const unsigned short* src = Ag + (size_t)(h * 128) * K + k0;
    unsigned short* dst = &As[q][0] + h * 8192 + tid * 8;
    load_lds16(src, dst);
    load_lds16(src + (size_t)64 * K, dst + 4096);
  };
  auto stageB = [&](int q, int h, int k0) {
    const unsigned short* src = Bg + (size_t)(h * 128) * K + k0;
    unsigned short* dst = &Bs[q][0] + h * 8192 + tid * 8;
    load_lds16(src, dst);
    load_lds16(src + (size_t)64 * K, dst + 4096);
  };

  floatx4 acc[8][4] = {};
  const int NT = K >> 6;

  // -------- prologue: tile0 (4 half-tiles) + tile1 (3 half-tiles) ----------
  stageA(0, 0, 0);  stageA(0, 1, 0);  stageB(0, 0, 0);  stageB(0, 1, 0);
  stageA(1, 0, 64); stageA(1, 1, 64); stageB(1, 0, 64);
  VMCNT6();   // retire tile0's 8 loads; tile1's 6 stay in flight
  BARRIER();

  for (int t = 0; t < NT; ++t) {
    const int q = t & 1;
    const unsigned short* pA = &As[q][0] + aoff;
    const unsigned short* pB = &Bs[q][0] + boff;
    const int k2 = (t + 2) << 6;
    const bool s2 = (t + 2) < NT;

    bf16x8 a0[4][2], a1[4][2], b0[2][2], b1[2][2];
    // ---------------- phase 1: (m0, n0) ----------------------------------
#pragma unroll
    for (int mi = 0; mi < 4; ++mi) {
      a0[mi][0] = *(const bf16x8*)(pA + mi * 1024 + xs0);
      a0[mi][1] = *(const bf16x8*)(pA + mi * 1024 + xs1);
    }
#pragma unroll
    for (int ni = 0; ni < 2; ++ni) {
      b0[ni][0] = *(const bf16x8*)(pB + ni * 1024 + xs0);
      b0[ni][1] = *(const bf16x8*)(pB + ni * 1024 + xs1);
    }
    if (t + 1 < NT) stageB(q ^ 1, 1, (t + 1) << 6);
    BARRIER();
    __builtin_amdgcn_s_setprio(1);
#pragma unroll
    for (int mi = 0; mi < 4; ++mi)
#pragma unroll
      for (int ni = 0; ni < 2; ++ni)
#pragma unroll
        for (int ks = 0; ks < 2; ++ks)
          acc[mi][ni] = __builtin_amdgcn_mfma_f32_16x16x32_bf16(
              a0[mi][ks], b0[ni][ks], acc[mi][ni], 0, 0, 0);
    __builtin_amdgcn_s_setprio(0);
    BARRIER();
    // ---------------- phase 2: (m1, n0) ----------------------------------
#pragma unroll
    for (int mi = 0; mi < 4; ++mi) {
      a1[mi][0] = *(const bf16x8*)(pA + (mi + 4) * 1024 + xs0);
      a1[mi][1] = *(const bf16x8*)(pA + (mi + 4) * 1024 + xs1);
    }
    BARRIER();
    __builtin_amdgcn_s_setprio(1);
#pragma unroll
    for (int mi = 0; mi < 4; ++mi)
#pragma unroll
      for (int ni = 0; ni < 2; ++ni)
#pragma unroll
        for (int ks = 0; ks < 2; ++ks)
          acc[mi + 4][ni] = __builtin_amdgcn_mfma_f32_16x16x32_bf16(
              a1[mi][ks], b0[ni][ks], acc[mi + 4][ni], 0, 0, 0);
    __builtin_amdgcn_s_setprio(0);
    BARRIER();
    // ---------------- phase 3: (m1, n1) ----------------------------------
#pragma unroll
    for (int ni = 0; ni < 2; ++ni) {
      b1[ni][0] = *(const bf16x8*)(pB + (ni + 2) * 1024 + xs0);
      b1[ni][1] = *(const bf16x8*)(pB + (ni + 2) * 1024 + xs1);
    }
    if (s2) stageA(q, 0, k2);
    BARRIER();
    __builtin_amdgcn_s_setprio(1);
#pragma unroll
    for (int mi = 0; mi < 4; ++mi)
#pragma unroll
      for (int ni = 0; ni < 2; ++ni)
#pragma unroll
        for (int ks = 0; ks < 2; ++ks)
          acc[mi + 4][ni + 2] = __builtin_amdgcn_mfma_f32_16x16x32_bf16(
              a1[mi][ks], b1[ni][ks], acc[mi + 4][ni + 2], 0, 0, 0);
    __builtin_amdgcn_s_setprio(0);
    BARRIER();
    // ---------------- phase 4: (m0, n1) ----------------------------------
    if (s2) { stageA(q, 1, k2); stageB(q, 0, k2); }
    BARRIER();
    __builtin_amdgcn_s_setprio(1);
#pragma unroll
    for (int mi = 0; mi < 4; ++mi)
#pragma unroll
      for (int ni = 0; ni < 2; ++ni)
#pragma unroll
        for (int ks = 0; ks < 2; ++ks)
          acc[mi][ni + 2] = __builtin_amdgcn_mfma_f32_16x16x32_bf16(
              a0[mi][ks], b1[ni][ks], acc[mi][ni + 2], 0, 0, 0);
    __builtin_amdgcn_s_setprio(0);
    if (t < NT - 2) { VMCNT6(); } else { VMCNT0(); }
    BARRIER();
  }

  // -------- epilogue -------------------------------------------------------
#pragma unroll
  for (int mi = 0; mi < 8; ++mi)
#pragma unroll
    for (int ni = 0; ni < 4; ++ni)
#pragma unroll
      for (int r = 0; r < 4; ++r) {
        const int gm = bm * 256 + wm * 128 + mi * 16 + quad * 4 + r;
        const int gn = bn * 256 + wn * 64 + ni * 16 + cl;
        const float v = acc[mi][ni][r];
        if (OUT_BF16)
          ((unsigned short*)Cout)[(size_t)gm * N + gn] = f2bf(v);
        else
          ((float*)Cout)[(size_t)gm * N + gn] = v;
      }
}

// ---------------- Fused RoPE + causal flash attention ----------------------
// grid (B*H=512, T/64=8), 256 threads = 4 waves, wave w owns q-rows w*16..+16.
// Softmax kept in log2 domain: log2(e)/sqrt(128) folded into Q scale.
__global__ __launch_bounds__(256) void attn_kernel(
    const unsigned short* __restrict__ qkv, const float* __restrict__ cost,
    const float* __restrict__ sint, unsigned short* __restrict__ y) {
  __shared__ __align__(16) unsigned short Qs[64][136];
  __shared__ __align__(16) unsigned short Ks[64][136];
  __shared__ __align__(16) unsigned short VTs[128][64];  // chunk-swizzled
  __shared__ __align__(16) unsigned short Ps[4][16][72];

  const int bh = blockIdx.x, qt = blockIdx.y;
  const int b = bh >> 4, h = bh & 15;
  const int tid = threadIdx.x, w = tid >> 6, l = tid & 63;
  const int quad = l >> 4, cl = l & 15;
  // 1/sqrt(128) * log2(e)  (softmax in exp2 domain)
  const float scale = 0.08838834764831845f * 1.4426950408889634f;

  // ---- Q tile: load + RoPE + scale, vector LDS writes ----
  {
    const int r = tid >> 2, j = tid & 3;
    const int tg = qt * 64 + r;
    const unsigned short* qrow = qkv + (size_t)(b * 512 + tg) * 6144 + h * 128;
    union { uint4 v; unsigned short u[8]; } c1, c2, p1, p2, o1, o2, o3, o4;
    c1.v = *(const uint4*)(qrow + j * 8);
    c2.v = *(const uint4*)(qrow + j * 8 + 32);
    p1.v = *(const uint4*)(qrow + 64 + j * 16);
    p2.v = *(const uint4*)(qrow + 64 + j * 16 + 8);
#pragma unroll
    for (int jj = 0; jj < 8; ++jj) {
      int d = j * 8 + jj;
      float c = cost[tg * 32 + d], s = sint[tg * 32 + d];
      float x1 = bf2f(c1.u[jj]), x2 = bf2f(c2.u[jj]);
      o1.u[jj] = f2bf((x1 * c - x2 * s) * scale);
      o2.u[jj] = f2bf((x2 * c + x1 * s) * scale);
      o3.u[jj] = f2bf(bf2f(p1.u[jj]) * scale);
      o4.u[jj] = f2bf(bf2f(p2.u[jj]) * scale);
    }
    *(uint4*)&Qs[r][j * 8]          = o1.v;
    *(uint4*)&Qs[r][j * 8 + 32]     = o2.v;
    *(uint4*)&Qs[r][64 + j * 16]     = o3.v;
    *(uint4*)&Qs[r][64 + j * 16 + 8] = o4.v;
  }

  floatx4 o[8] = {};
  float m_i[4] = {-__builtin_inff(), -__builtin_inff(), -__builtin_inff(),
                  -__builtin_inff()};
  float l_i[4] = {0.f, 0.f, 0.f, 0.f};

  for (int ktile = 0; ktile <= qt; ++ktile) {
    __syncthreads();  // (A) previous PV done reading Ks/VTs
    {  // K tile: load + RoPE, vector LDS writes
      const int r = tid >> 2, j = tid & 3;
      const int tg = ktile * 64 + r;
      const unsigned short* krow =
          qkv + (size_t)(b * 512 + tg) * 6144 + 2048 + h * 128;
      union { uint4 v; unsigned short u[8]; } c1, c2, p1, p2, o1, o2;
      c1.v = *(const uint4*)(krow + j * 8);
      c2.v = *(const uint4*)(krow + j * 8 + 32);
      p1.v = *(const uint4*)(krow + 64 + j * 16);
      p2.v = *(const uint4*)(krow + 64 + j * 16 + 8);
#pragma unroll
      for (int jj = 0; jj < 8; ++jj) {
        int d = j * 8 + jj;
        float c = cost[tg * 32 + d], s = sint[tg * 32 + d];
        float x1 = bf2f(c1.u[jj]), x2 = bf2f(c2.u[jj]);
        o1.u[jj] = f2bf(x1 * c - x2 * s);
        o2.u[jj] = f2bf(x2 * c + x1 * s);
      }
      *(uint4*)&Ks[r][j * 8]          = o1.v;
      *(uint4*)&Ks[r][j * 8 + 32]     = o2.v;
      *(uint4*)&Ks[r][64 + j * 16]     = p1.v;
      *(uint4*)&Ks[r][64 + j * 16 + 8] = p2.v;
    }
    {  // V tile -> VTs[d][kk'], 8 kk-rows x 4 d-cols per thread, swizzled
      const int rowg = tid >> 5;        // kk0 = rowg*8
      const int colg = tid & 31;        // d0 = colg*4
      const int kk0 = rowg * 8, d0 = colg * 4;
      const unsigned short* vbase = qkv +
          (size_t)(b * 512 + ktile * 64 + kk0) * 6144 + 4096 + h * 128 + d0;
      uint2 rv[8];
#pragma unroll
      for (int rr = 0; rr < 8; ++rr)
        rv[rr] = *(const uint2*)(vbase + (size_t)rr * 6144);
#pragma unroll
      for (int c = 0; c < 4; ++c) {
        const int d = d0 + c;
        unsigned out[4];
#pragma unroll
        for (int p = 0; p < 4; ++p) {
          unsigned ua = ((const unsigned*)&rv[2 * p])[c >> 1];
          unsigned ub = ((const unsigned*)&rv[2 * p + 1])[c >> 1];
          unsigned lo = (c & 1) ? (ua >> 16) : (ua & 0xffffu);
          unsigned hi = (c & 1) ? (ub >> 16) : (ub & 0xffffu);
          out[p] = lo | (hi << 16);
        }
        *(uint4*)&VTs[d][(rowg ^ (d & 7)) << 3] = *(uint4*)out;
      }
    }
    __syncthreads();  // (B) staging complete

    // S = Q K^T : wave w -> 16x64 strip
    floatx4 s[4] = {};
#pragma unroll
    for (int kc = 0; kc < 4; ++kc) {
      bf16x8 aq = *(const bf16x8*)(&Qs[w * 16 + cl][kc * 32 + quad * 8]);
#pragma unroll
      for (int nt = 0; nt < 4; ++nt) {
        bf16x8 bk = *(const bf16x8*)(&Ks[nt * 16 + cl][kc * 32 + quad * 8]);
        s[nt] = __builtin_amdgcn_mfma_f32_16x16x32_bf16(aq, bk, s[nt], 0, 0, 0);
      }
    }
    if (ktile == qt) {  // causal mask on diagonal tile
#pragma unroll
      for (int nt = 0; nt < 4; ++nt)
#pragma unroll
        for (int r = 0; r < 4; ++r) {
          int qrow_l = w * 16 + quad * 4 + r;
          int kcol_l = nt * 16 + cl;
          if (kcol_l > qrow_l) s[nt][r] = -__builtin_inff();
        }
    }
    // online softmax (exp2 domain)
#pragma unroll
    for (int r = 0; r < 4; ++r) {
      float mx = fmaxf(fmaxf(s[0][r], s[1][r]), fmaxf(s[2][r], s[3][r]));
      mx = fmaxf(mx, __shfl_xor(mx, 1));
      mx = fmaxf(mx, __shfl_xor(mx, 2));
      mx = fmaxf(mx, __shfl_xor(mx, 4));
      mx = fmaxf(mx, __shfl_xor(mx, 8));
      float mn = fmaxf(m_i[r], mx);
      float a = exp2f(m_i[r] - mn);
      float rs = 0.f;
#pragma unroll
      for (int nt = 0; nt < 4; ++nt) {
        float p = exp2f(s[nt][r] - mn);
        s[nt][r] = p;
        rs += p;
      }
      rs += __shfl_xor(rs, 1);
      rs += __shfl_xor(rs, 2);
      rs += __shfl_xor(rs, 4);
      rs += __shfl_xor(rs, 8);
      l_i[r] = l_i[r] * a + rs;
      m_i[r] = mn;
#pragma unroll
      for (int nt2 = 0; nt2 < 8; ++nt2) o[nt2][r] *= a;
#pragma unroll
      for (int nt = 0; nt < 4; ++nt)
        Ps[w][quad * 4 + r][nt * 16 + cl] = f2bf(s[nt][r]);
    }
    __syncthreads();  // (C) P visible (VTs still valid)

    // O += P V  (B operand from swizzled VTs)
#pragma unroll
    for (int kc2 = 0; kc2 < 2; ++kc2) {
      bf16x8 ap = *(const bf16x8*)(&Ps[w][cl][kc2 * 32 + quad * 8]);
#pragma unroll
      for (int nt2 = 0; nt2 < 8; ++nt2) {
        bf16x8 bv = *(const bf16x8*)(
            &VTs[nt2 * 16 + cl][((kc2 * 4 + quad) ^ (cl & 7)) << 3]);
        o[nt2] = __builtin_amdgcn_mfma_f32_16x16x32_bf16(ap, bv, o[nt2], 0, 0, 0);
      }
    }
  }

  // epilogue: y[bt][h*128+d] = o/l
#pragma unroll
  for (int r = 0; r < 4; ++r) {
    float inv = 1.0f / l_i[r];
    size_t row =
        (size_t)(b * 512 + qt * 64 + w * 16 + quad * 4 + r) * 2048 + h * 128;
#pragma unroll
    for (int nt2 = 0; nt2 < 8; ++nt2)
      y[row + nt2 * 16 + cl] = f2bf(o[nt2][r] * inv);
  }
}

// ---------------------------------------------------------------------------
extern "C" void kernel_launch(void* const* d_in, const int* in_sizes, int n_in,
                              void* d_out, int out_size, void* d_ws,
                              size_t ws_size, hipStream_t stream) {
  const float* x = (const float*)d_in[0];
  const float* wqkv = (const float*)d_in[1];
  const float* wout = (const float*)d_in[2];
  float* out = (float*)d_out;

  char* ws = (char*)d_ws;
  float* cost = (float*)ws;            ws += (size_t)512 * 32 * 4;
  float* sint = (float*)ws;            ws += (size_t)512 * 32 * 4;
  unsigned short* xb = (unsigned short*)ws;    ws += (size_t)16384 * 2048 * 2;
  unsigned short* wqkvb = (unsigned short*)ws; ws += (size_t)6144 * 2048 * 2;
  unsigned short* woutb = (unsigned short*)ws; ws += (size_t)2048 * 2048 * 2;
  unsigned short* qkvb = (unsigned short*)ws;  ws += (size_t)16384 * 6144 * 2;
  unsigned short* yb = (unsigned short*)ws;    ws += (size_t)16384 * 2048 * 2;

  rope_tables<<<dim3(64), dim3(256), 0, stream>>>(cost, sint);
  cast_bf16<<<dim3(16384), dim3(256), 0, stream>>>(x, xb, 33554432 / 8);
  cast_bf16<<<dim3(6144), dim3(256), 0, stream>>>(wqkv, wqkvb, 12582912 / 8);
  cast_bf16<<<dim3(2048), dim3(256), 0, stream>>>(wout, woutb, 4194304 / 8);
  gemm256<1><<<dim3(24, 64), dim3(512), 0, stream>>>(xb, wqkvb, (void*)qkvb,
                                                     16384, 6144, 2048);
  attn_kernel<<<dim3(512, 8), dim3(256), 0, stream>>>(qkvb, cost, sint, yb);
  gemm256<0><<<dim3(8, 64), dim3(512), 0, stream>>>(yb, woutb, (void*)out,
                                                    16384, 2048, 2048);
}